// Round 1
// baseline (304.786 us; speedup 1.0000x reference)
//
#include <hip/hip_runtime.h>
#include <math.h>

#define O_  32
#define I_  32
#define K_  13
#define N_  4096
#define IK  (I_ * K_)     // 416
#define OIK (O_ * IK)     // 13312

__global__ __launch_bounds__(256) void plaq_kernel(
    const float* __restrict__ x,      // (I, N)
    const float* __restrict__ W,      // (O, I, K)
    const float* __restrict__ b,      // (O,)
    const float* __restrict__ mask,   // (N, O, I, K)
    const int*   __restrict__ shifts, // (N, K)
    float* __restrict__ out)          // (O, N)
{
    __shared__ __align__(16) float g_lds[IK];
    const int n   = blockIdx.x;
    const int tid = threadIdx.x;

    // Gather g[i*13+k] = x[i*N + shifts[n*13+k]] into LDS (416 floats).
    for (int idx = tid; idx < IK; idx += 256) {
        int i = idx / K_;
        int k = idx - i * K_;
        int s = shifts[n * K_ + k];
        g_lds[idx] = x[i * N_ + s];
    }
    __syncthreads();

    // 8 threads per o; each thread reads 13 float4s of its o-chunk.
    const int o  = tid >> 3;
    const int s8 = tid & 7;
    const float4* m4 = (const float4*)(mask + (size_t)n * OIK + o * IK);
    const float4* w4 = (const float4*)(W + o * IK);
    const float4* g4 = (const float4*)g_lds;

    float acc = 0.0f;
#pragma unroll
    for (int m = 0; m < 13; ++m) {
        int j = s8 + 8 * m;          // float4 index within o-chunk [0,104)
        float4 mv = m4[j];
        float4 wv = w4[j];
        float4 gv = g4[j];
        acc += mv.x * wv.x * gv.x;
        acc += mv.y * wv.y * gv.y;
        acc += mv.z * wv.z * gv.z;
        acc += mv.w * wv.w * gv.w;
    }

    // Reduce across the 8 lanes sharing this o.
    acc += __shfl_down(acc, 4);
    acc += __shfl_down(acc, 2);
    acc += __shfl_down(acc, 1);

    if (s8 == 0) {
        const float scale = (float)((2.0 + 2.0 * M_E) / (M_E - 1.0));
        float y  = acc + b[o];
        float sg = 1.0f / (1.0f + __expf(-y));
        out[o * N_ + n] = (sg - 0.5f) * scale;
    }
}

extern "C" void kernel_launch(void* const* d_in, const int* in_sizes, int n_in,
                              void* d_out, int out_size, void* d_ws, size_t ws_size,
                              hipStream_t stream) {
    const float* x      = (const float*)d_in[0];
    const float* Wconv  = (const float*)d_in[1];
    const float* bconv  = (const float*)d_in[2];
    const float* mask   = (const float*)d_in[3];
    const int*   shifts = (const int*)d_in[4];
    float* out = (float*)d_out;

    plaq_kernel<<<N_, 256, 0, stream>>>(x, Wconv, bconv, mask, shifts, out);
}

// Round 3
// 297.967 us; speedup vs baseline: 1.0229x; 1.0229x over previous
//
#include <hip/hip_runtime.h>
#include <math.h>

#define O_  32
#define I_  32
#define K_  13
#define N_  4096
#define IK  (I_ * K_)     // 416
#define OIK (O_ * IK)     // 13312
#define NB  2             // n's per block

typedef float f32x4 __attribute__((ext_vector_type(4)));

__global__ __launch_bounds__(256, 3) void plaq_kernel(
    const float* __restrict__ x,      // (I, N)
    const float* __restrict__ W,      // (O, I, K)
    const float* __restrict__ b,      // (O,)
    const float* __restrict__ mask,   // (N, O, I, K)
    const int*   __restrict__ shifts, // (N, K)
    float* __restrict__ out)          // (O, N)
{
    __shared__ __align__(16) float g_lds[NB][IK];
    const int n0  = blockIdx.x * NB;
    const int tid = threadIdx.x;

    // Gather g[nl][i*13+k] = x[i*N + shifts[(n0+nl)*13+k]] into LDS.
    for (int idx = tid; idx < NB * IK; idx += 256) {
        int nl = idx / IK;
        int r  = idx - nl * IK;
        int i  = r / K_;
        int k  = r - i * K_;
        int s  = shifts[(n0 + nl) * K_ + k];
        g_lds[nl][r] = x[i * N_ + s];
    }
    __syncthreads();

    // 8 threads per o; each thread owns float4 lanes j = s8 + 8m, m=0..12.
    const int o  = tid >> 3;
    const int s8 = tid & 7;
    const f32x4* w4 = (const f32x4*)(W + o * IK);
    const float scale = (float)((2.0 + 2.0 * M_E) / (M_E - 1.0));

    for (int nl = 0; nl < NB; ++nl) {
        const int n = n0 + nl;
        const f32x4* m4 = (const f32x4*)(mask + (size_t)n * OIK + o * IK);
        const f32x4* g4 = (const f32x4*)(&g_lds[nl][0]);

        // Hoist W*g out of the streaming loop (W from L2, g from LDS).
        f32x4 wg[13];
#pragma unroll
        for (int m = 0; m < 13; ++m) {
            int j = s8 + 8 * m;
            wg[m] = w4[j] * g4[j];
        }

        // Hot loop: one nontemporal mask load + 4 FMAs per iteration.
        float acc = 0.0f;
#pragma unroll
        for (int m = 0; m < 13; ++m) {
            f32x4 mv = __builtin_nontemporal_load(&m4[s8 + 8 * m]);
            acc = fmaf(mv.x, wg[m].x, acc);
            acc = fmaf(mv.y, wg[m].y, acc);
            acc = fmaf(mv.z, wg[m].z, acc);
            acc = fmaf(mv.w, wg[m].w, acc);
        }

        // Reduce across the 8 lanes sharing this o (within one wave).
        acc += __shfl_down(acc, 4);
        acc += __shfl_down(acc, 2);
        acc += __shfl_down(acc, 1);

        if (s8 == 0) {
            float y  = acc + b[o];
            float sg = 1.0f / (1.0f + __expf(-y));
            out[o * N_ + n] = (sg - 0.5f) * scale;
        }
    }
}

extern "C" void kernel_launch(void* const* d_in, const int* in_sizes, int n_in,
                              void* d_out, int out_size, void* d_ws, size_t ws_size,
                              hipStream_t stream) {
    const float* x      = (const float*)d_in[0];
    const float* Wconv  = (const float*)d_in[1];
    const float* bconv  = (const float*)d_in[2];
    const float* mask   = (const float*)d_in[3];
    const int*   shifts = (const int*)d_in[4];
    float* out = (float*)d_out;

    plaq_kernel<<<N_ / NB, 256, 0, stream>>>(x, Wconv, bconv, mask, shifts, out);
}